// Round 1
// baseline (621.120 us; speedup 1.0000x reference)
//
#include <hip/hip_runtime.h>
#include <math.h>

// ---------------------------------------------------------------------------
// QASS Multihead Attention, MI355X (gfx950)
// B=2, N=2048, D=1024, H=16, Dh=64, HID=64. Output fp32 [B,N,D].
//
// Precision plan (absmax threshold 7.06e-2, QASS base scaling ~5x on q):
//  - q,k projections + QK^T: split-bf16 (hi+lo, 3 MFMAs) -> ~fp32 accuracy
//  - v projection, P*V, out projection: plain bf16 (error contribution ~4e-3)
//  - gate MLP / base / softmax: fp32 VALU
// ---------------------------------------------------------------------------

using bhalf8  = __attribute__((ext_vector_type(8))) short;   // 8 bf16 = 4 VGPRs
using floatx4 = __attribute__((ext_vector_type(4))) float;   // MFMA C/D

__device__ inline unsigned short f2bf(float f) {
  union { float f; unsigned int u; } v; v.f = f;
  unsigned int u = v.u;
  u = u + 0x7fffu + ((u >> 16) & 1u);          // round-to-nearest-even
  return (unsigned short)(u >> 16);
}
__device__ inline float bf2f(unsigned short h) {
  union { unsigned int u; float f; } v; v.u = ((unsigned int)h) << 16;
  return v.f;
}
__device__ inline float gelu_f(float x) {      // exact (erf) GELU, torch default
  return 0.5f * x * (1.0f + erff(x * 0.70710678118654752440f));
}

#define MFMA16(a, b, c) __builtin_amdgcn_mfma_f32_16x16x32_bf16((a), (b), (c), 0, 0, 0)

// ---------------------------------------------------------------------------
// base[1024] = gelu(log(n) * wb1) @ wb2.T     (wb2: [1024,64])
// ---------------------------------------------------------------------------
__global__ __launch_bounds__(256) void k_base(const float* __restrict__ wb1,
                                              const float* __restrict__ wb2,
                                              const int* __restrict__ nctx,
                                              float* __restrict__ base_out) {
  __shared__ float h1[64];
  int tid = threadIdx.x;
  float logn = logf((float)(*nctx));
  if (tid < 64) h1[tid] = gelu_f(logn * wb1[tid]);
  __syncthreads();
  int i = blockIdx.x * 256 + tid;              // 0..1023 over 4 blocks
  float s = 0.f;
#pragma unroll
  for (int j = 0; j < 64; j++) s += h1[j] * wb2[i * 64 + j];
  base_out[i] = s;
}

// ---------------------------------------------------------------------------
// GEMM  C[4096,1024] = A[4096,1024] @ W[1024,1024]^T   (torch Linear)
// Tile 128x64, BK=32, 256 threads = 4 waves (2x2), each wave 64x32.
// MODE 0: A fp32 split, W split  -> qf32 scatter to [B,H,N,Dh] fp32
// MODE 1: A fp32 split, W split  -> khi/klo bf16 scatter to [B,H,N,Dh]
// MODE 2: A fp32 hi,    W hi     -> vbf bf16 scatter to [B,H,N,Dh]
// MODE 3: A bf16 direct,W hi     -> fp32 row-major [4096,1024] (d_out)
// ---------------------------------------------------------------------------
template <int MODE>
__global__ __launch_bounds__(256) void k_gemm(const void* __restrict__ Ap,
                                              const float* __restrict__ Wp,
                                              void* __restrict__ out0,
                                              void* __restrict__ out1) {
  constexpr bool SPLIT = (MODE == 0 || MODE == 1);
  constexpr int LDP = 40;                      // padded LDS stride (bf16 elems)
  __shared__ __align__(16) unsigned short Ah[128 * LDP];
  __shared__ __align__(16) unsigned short Al[128 * LDP];
  __shared__ __align__(16) unsigned short Bh[64 * LDP];
  __shared__ __align__(16) unsigned short Bl[64 * LDP];

  const int tid = threadIdx.x;
  const int lane = tid & 63;
  const int w = tid >> 6;
  const int quad = lane >> 4;
  const int lm = lane & 15;
  const int wm = w >> 1;                       // 0..1 (64-row half)
  const int wn = w & 1;                        // 0..1 (32-col half)
  const int bm0 = blockIdx.y * 128;
  const int bn0 = blockIdx.x * 64;

  // staging assignments
  const int rA = tid >> 1;                     // 0..127
  const int cA = (tid & 1) * 16;               // 0 or 16
  const int rB = tid >> 2;                     // 0..63
  const int cB = (tid & 3) * 8;                // 0,8,16,24

  const floatx4 zero4 = {0.f, 0.f, 0.f, 0.f};
  floatx4 acc[4][2];
#pragma unroll
  for (int i = 0; i < 4; i++)
#pragma unroll
    for (int j = 0; j < 2; j++) acc[i][j] = zero4;

  for (int kk = 0; kk < 1024; kk += 32) {
    __syncthreads();
    // ---- stage A tile (128 x 32) ----
    if constexpr (MODE == 3) {
      const unsigned short* Ab = (const unsigned short*)Ap;
      const unsigned short* src = Ab + (size_t)(bm0 + rA) * 1024 + kk + cA;
      *(bhalf8*)&Ah[rA * LDP + cA]     = *(const bhalf8*)(src);
      *(bhalf8*)&Ah[rA * LDP + cA + 8] = *(const bhalf8*)(src + 8);
    } else {
      const float* Af = (const float*)Ap;
      const float4* s4 = (const float4*)(Af + (size_t)(bm0 + rA) * 1024 + kk + cA);
      float4 x0 = s4[0], x1 = s4[1], x2 = s4[2], x3 = s4[3];
      float f[16] = {x0.x, x0.y, x0.z, x0.w, x1.x, x1.y, x1.z, x1.w,
                     x2.x, x2.y, x2.z, x2.w, x3.x, x3.y, x3.z, x3.w};
      bhalf8 h0, h1, l0, l1;
#pragma unroll
      for (int i = 0; i < 8; i++) {
        unsigned short a = f2bf(f[i]);     h0[i] = (short)a;
        unsigned short b = f2bf(f[8 + i]); h1[i] = (short)b;
        if constexpr (SPLIT) {
          l0[i] = (short)f2bf(f[i]     - bf2f(a));
          l1[i] = (short)f2bf(f[8 + i] - bf2f(b));
        }
      }
      *(bhalf8*)&Ah[rA * LDP + cA]     = h0;
      *(bhalf8*)&Ah[rA * LDP + cA + 8] = h1;
      if constexpr (SPLIT) {
        *(bhalf8*)&Al[rA * LDP + cA]     = l0;
        *(bhalf8*)&Al[rA * LDP + cA + 8] = l1;
      }
    }
    // ---- stage W tile (64 rows x 32) : row n of W == B-operand col n ----
    {
      const float4* s4 = (const float4*)(Wp + (size_t)(bn0 + rB) * 1024 + kk + cB);
      float4 x0 = s4[0], x1 = s4[1];
      float f[8] = {x0.x, x0.y, x0.z, x0.w, x1.x, x1.y, x1.z, x1.w};
      bhalf8 h0, l0;
#pragma unroll
      for (int i = 0; i < 8; i++) {
        unsigned short a = f2bf(f[i]); h0[i] = (short)a;
        if constexpr (SPLIT) l0[i] = (short)f2bf(f[i] - bf2f(a));
      }
      *(bhalf8*)&Bh[rB * LDP + cB] = h0;
      if constexpr (SPLIT) *(bhalf8*)&Bl[rB * LDP + cB] = l0;
    }
    __syncthreads();

    // ---- fragments + MFMA ----
    bhalf8 ah[4], al[4], bh_[2], bl_[2];
#pragma unroll
    for (int tm = 0; tm < 4; tm++) {
      int r = wm * 64 + tm * 16 + lm;
      ah[tm] = *(const bhalf8*)&Ah[r * LDP + quad * 8];
      if constexpr (SPLIT) al[tm] = *(const bhalf8*)&Al[r * LDP + quad * 8];
    }
#pragma unroll
    for (int tn = 0; tn < 2; tn++) {
      int c = wn * 32 + tn * 16 + lm;
      bh_[tn] = *(const bhalf8*)&Bh[c * LDP + quad * 8];
      if constexpr (SPLIT) bl_[tn] = *(const bhalf8*)&Bl[c * LDP + quad * 8];
    }
#pragma unroll
    for (int tm = 0; tm < 4; tm++)
#pragma unroll
      for (int tn = 0; tn < 2; tn++) {
        acc[tm][tn] = MFMA16(ah[tm], bh_[tn], acc[tm][tn]);
        if constexpr (SPLIT) {
          acc[tm][tn] = MFMA16(ah[tm], bl_[tn], acc[tm][tn]);
          acc[tm][tn] = MFMA16(al[tm], bh_[tn], acc[tm][tn]);
        }
      }
  }

  // ---- epilogue: C row = quad*4+rr, col = lm (m89/m91-verified layout) ----
#pragma unroll
  for (int tm = 0; tm < 4; tm++)
#pragma unroll
    for (int tn = 0; tn < 2; tn++)
#pragma unroll
      for (int rr = 0; rr < 4; rr++) {
        int gm = bm0 + wm * 64 + tm * 16 + quad * 4 + rr;   // 0..4095 = b*2048+n
        int gn = bn0 + wn * 32 + tn * 16 + lm;              // 0..1023 = h*64+d
        float v = acc[tm][tn][rr];
        if constexpr (MODE == 3) {
          ((float*)out0)[(size_t)gm * 1024 + gn] = v;
        } else {
          int b = gm >> 11, n = gm & 2047, hd = gn >> 6, d = gn & 63;
          size_t idx = ((size_t)((b << 4) + hd) * 2048 + n) * 64 + d;
          if constexpr (MODE == 0) {
            ((float*)out0)[idx] = v;
          } else if constexpr (MODE == 1) {
            unsigned short hh = f2bf(v);
            ((unsigned short*)out0)[idx] = hh;
            ((unsigned short*)out1)[idx] = f2bf(v - bf2f(hh));
          } else {
            ((unsigned short*)out0)[idx] = f2bf(v);
          }
        }
      }
}

// ---------------------------------------------------------------------------
// Gate MLP (fp32) + QASS scaling + 1/8 score prescale + hi/lo split store.
// One wave per (b,h,n) row of 64. qs = q * base[h,d] * (1+tanh(mlp(q))) / 8
// ---------------------------------------------------------------------------
__global__ __launch_bounds__(256) void k_gate(const float* __restrict__ qf32,
                                              const float* __restrict__ base_v,
                                              const float* __restrict__ wg1,
                                              const float* __restrict__ wg2,
                                              unsigned short* __restrict__ qhi,
                                              unsigned short* __restrict__ qlo) {
  __shared__ float w1[64 * 65];   // pad 65: banks (j+d)%32 -> 2-way (free)
  __shared__ float w2[64 * 65];
  __shared__ float qr[4][64];
  __shared__ float gr[4][64];
  int tid = threadIdx.x;
  for (int i = tid; i < 4096; i += 256) {
    w1[(i >> 6) * 65 + (i & 63)] = wg1[i];
    w2[(i >> 6) * 65 + (i & 63)] = wg2[i];
  }
  int w = tid >> 6, lane = tid & 63;
  size_t row = (size_t)blockIdx.x * 4 + w;          // 0..65535 = (b*16+h)*2048+n
  float qv = qf32[row * 64 + lane];
  qr[w][lane] = qv;
  __syncthreads();
  float h = 0.f;                                     // lane = hidden index j
#pragma unroll
  for (int d = 0; d < 64; d++) h += qr[w][d] * w1[lane * 65 + d];
  gr[w][lane] = gelu_f(h);
  __syncthreads();
  float t = 0.f;                                     // lane = output index d
#pragma unroll
  for (int j = 0; j < 64; j++) t += gr[w][j] * w2[lane * 65 + j];
  float gate = 1.0f + tanhf(t);
  int hd = (int)((row >> 11) & 15);
  float qs = qv * base_v[hd * 64 + lane] * gate * 0.125f;  // fold 1/sqrt(Dh)
  unsigned short hh = f2bf(qs);
  qhi[row * 64 + lane] = hh;
  qlo[row * 64 + lane] = f2bf(qs - bf2f(hh));
}

// ---------------------------------------------------------------------------
// Flash attention. Block = (qtile of 64 rows, h, b), 4 waves x 16 q-rows.
// K-loop: 64 iters x 32 keys. QK^T split-bf16 (3 MFMAs), online softmax,
// P -> LDS -> A-frag, V transposed in LDS -> B-frag, O += P V.
// ---------------------------------------------------------------------------
__global__ __launch_bounds__(256) void k_attn(const unsigned short* __restrict__ qhi,
                                              const unsigned short* __restrict__ qlo,
                                              const unsigned short* __restrict__ khi,
                                              const unsigned short* __restrict__ klo,
                                              const unsigned short* __restrict__ vbf,
                                              unsigned short* __restrict__ obf) {
  constexpr int LDP = 40;
  __shared__ __align__(16) unsigned short vT[64 * LDP];    // [d][key]
  __shared__ __align__(16) unsigned short pl[4 * 16 * LDP]; // per-wave P tiles

  const int tid = threadIdx.x;
  const int lane = tid & 63;
  const int w = tid >> 6;
  const int quad = lane >> 4;
  const int lm = lane & 15;
  const int qt = blockIdx.x, hd = blockIdx.y, b = blockIdx.z;
  const int bh = b * 16 + hd;
  const size_t hb = (size_t)bh * 2048 * 64;

  // Q fragments (A-operand: m=lm, k=quad*8+j), held in regs for whole loop
  const int qrow = qt * 64 + w * 16 + lm;
  bhalf8 qh[2], ql_[2];
#pragma unroll
  for (int kc = 0; kc < 2; kc++) {
    size_t off = hb + (size_t)qrow * 64 + kc * 32 + quad * 8;
    qh[kc]  = *(const bhalf8*)(qhi + off);
    ql_[kc] = *(const bhalf8*)(qlo + off);
  }

  const floatx4 zero4 = {0.f, 0.f, 0.f, 0.f};
  floatx4 O[4];
#pragma unroll
  for (int dt = 0; dt < 4; dt++) O[dt] = zero4;
  float m_i[4], l_i[4];
#pragma unroll
  for (int r = 0; r < 4; r++) { m_i[r] = -INFINITY; l_i[r] = 0.f; }

  unsigned short* plw = &pl[w * 16 * LDP];

  for (int kt = 0; kt < 64; kt++) {
    const int kb0 = kt * 32;
    __syncthreads();                       // vT safe to overwrite
    {                                      // stage V transposed: vT[d][key]
      int key = tid >> 3, ds = (tid & 7) * 8;
      bhalf8 vv = *(const bhalf8*)(vbf + hb + (size_t)(kb0 + key) * 64 + ds);
#pragma unroll
      for (int j = 0; j < 8; j++) vT[(ds + j) * LDP + key] = (unsigned short)vv[j];
    }
    __syncthreads();

    // scores S (C-layout: row=quad*4+rr, col=lm), scale already folded into q
    floatx4 s[2];
#pragma unroll
    for (int kb = 0; kb < 2; kb++) {
      floatx4 sa = zero4;
      int key = kb0 + kb * 16 + lm;
      const unsigned short* kh_p = khi + hb + (size_t)key * 64;
      const unsigned short* kl_p = klo + hb + (size_t)key * 64;
#pragma unroll
      for (int kc = 0; kc < 2; kc++) {
        bhalf8 kh = *(const bhalf8*)(kh_p + kc * 32 + quad * 8);
        bhalf8 kl = *(const bhalf8*)(kl_p + kc * 32 + quad * 8);
        sa = MFMA16(qh[kc], kh, sa);
        sa = MFMA16(qh[kc], kl, sa);
        sa = MFMA16(ql_[kc], kh, sa);
      }
      s[kb] = sa;
    }

    // online softmax per row rr (mask is all-true -> ignored)
#pragma unroll
    for (int rr = 0; rr < 4; rr++) {
      float mx = fmaxf(s[0][rr], s[1][rr]);
      mx = fmaxf(mx, __shfl_xor(mx, 1, 64));
      mx = fmaxf(mx, __shfl_xor(mx, 2, 64));
      mx = fmaxf(mx, __shfl_xor(mx, 4, 64));
      mx = fmaxf(mx, __shfl_xor(mx, 8, 64));
      float newm = fmaxf(m_i[rr], mx);
      float alpha = __expf(m_i[rr] - newm);
      float p0 = __expf(s[0][rr] - newm);
      float p1 = __expf(s[1][rr] - newm);
      float rs = p0 + p1;
      rs += __shfl_xor(rs, 1, 64);
      rs += __shfl_xor(rs, 2, 64);
      rs += __shfl_xor(rs, 4, 64);
      rs += __shfl_xor(rs, 8, 64);
      l_i[rr] = l_i[rr] * alpha + rs;
      m_i[rr] = newm;
#pragma unroll
      for (int dt = 0; dt < 4; dt++) O[dt][rr] *= alpha;
      int prow = quad * 4 + rr;
      plw[prow * LDP + lm]      = f2bf(p0);
      plw[prow * LDP + 16 + lm] = f2bf(p1);
    }
    __syncthreads();                       // P visible (and waves aligned)

    // O += P @ V   (A = P: m=lm rows; B = V^T in LDS)
    bhalf8 pf = *(const bhalf8*)&plw[lm * LDP + quad * 8];
#pragma unroll
    for (int dt = 0; dt < 4; dt++) {
      bhalf8 vf = *(const bhalf8*)&vT[(dt * 16 + lm) * LDP + quad * 8];
      O[dt] = MFMA16(pf, vf, O[dt]);
    }
  }

  // epilogue: obf[(b*2048+n)][h*64+d] bf16
#pragma unroll
  for (int dt = 0; dt < 4; dt++)
#pragma unroll
    for (int rr = 0; rr < 4; rr++) {
      float v = O[dt][rr] / l_i[rr];
      int n = qt * 64 + w * 16 + quad * 4 + rr;
      size_t orow = (size_t)b * 2048 + n;
      int col = hd * 64 + dt * 16 + lm;
      obf[orow * 1024 + col] = f2bf(v);
    }
}

// ---------------------------------------------------------------------------
extern "C" void kernel_launch(void* const* d_in, const int* in_sizes, int n_in,
                              void* d_out, int out_size, void* d_ws, size_t ws_size,
                              hipStream_t stream) {
  const float* query = (const float*)d_in[0];
  const float* key_  = (const float*)d_in[1];
  const float* value = (const float*)d_in[2];
  // d_in[3] allowed_mask: all-true in this problem -> ignored
  const float* wq  = (const float*)d_in[4];
  const float* wk  = (const float*)d_in[5];
  const float* wv  = (const float*)d_in[6];
  const float* wo  = (const float*)d_in[7];
  const float* wb1 = (const float*)d_in[8];
  const float* wb2 = (const float*)d_in[9];
  const float* wg1 = (const float*)d_in[10];
  const float* wg2 = (const float*)d_in[11];
  const int* nctx  = (const int*)d_in[12];
  float* out = (float*)d_out;

  char* ws = (char*)d_ws;
  size_t o = 0;
  float* base_v = (float*)(ws + o); o += 4096;
  float* qf32   = (float*)(ws + o); o += (size_t)4096 * 1024 * 4;
  unsigned short* qhi = (unsigned short*)(ws + o); o += (size_t)4096 * 1024 * 2;
  unsigned short* qlo = (unsigned short*)(ws + o); o += (size_t)4096 * 1024 * 2;
  unsigned short* khi = (unsigned short*)(ws + o); o += (size_t)4096 * 1024 * 2;
  unsigned short* klo = (unsigned short*)(ws + o); o += (size_t)4096 * 1024 * 2;
  unsigned short* vbf = (unsigned short*)(ws + o); o += (size_t)4096 * 1024 * 2;
  unsigned short* obf = (unsigned short*)(ws + o); o += (size_t)4096 * 1024 * 2;

  dim3 gg(16, 32);   // N/64 x M/128
  k_base<<<4, 256, 0, stream>>>(wb1, wb2, nctx, base_v);
  k_gemm<0><<<gg, 256, 0, stream>>>(query, wq, qf32, nullptr);
  k_gemm<1><<<gg, 256, 0, stream>>>(key_, wk, khi, klo);
  k_gemm<2><<<gg, 256, 0, stream>>>(value, wv, vbf, nullptr);
  k_gate<<<16384, 256, 0, stream>>>(qf32, base_v, wg1, wg2, qhi, qlo);
  k_attn<<<dim3(32, 16, 2), 256, 0, stream>>>(qhi, qlo, khi, klo, vbf, obf);
  k_gemm<3><<<gg, 256, 0, stream>>>(obf, wo, out, nullptr);
}